// Round 3
// baseline (694.481 us; speedup 1.0000x reference)
//
#include <hip/hip_runtime.h>
#include <math.h>

// Problem constants (fixed by reference).
#define TOKENS      16384     // 8 * 2048
#define HID         2048
#define EXPERTS     64
#define CAPSLOT     1024      // per-expert list cap; counts ~Binom(16384,1/64)=256±16
#define CAP         512       // expert_capacity = 2*ceil(16384/64)

__device__ __forceinline__ void fma8(float* a, float s, float4 w0, float4 w1) {
    a[0] = fmaf(s, w0.x, a[0]); a[1] = fmaf(s, w0.y, a[1]);
    a[2] = fmaf(s, w0.z, a[2]); a[3] = fmaf(s, w0.w, a[3]);
    a[4] = fmaf(s, w1.x, a[4]); a[5] = fmaf(s, w1.y, a[5]);
    a[6] = fmaf(s, w1.z, a[6]); a[7] = fmaf(s, w1.w, a[7]);
}

// ---------------------------------------------------------------------------
// K1: fused logits GEMM + softmax + top1/top2 routing.
// Grid = 1024 blocks x 256 threads (4 waves). Block owns 16 tokens, full K.
// Wave w computes k-chunk [w*512, w*512+512): 16 tokens x 64 experts,
// thread tile 2 tokens x 8 experts = 16 fp32 acc. Explicit register
// prefetch of next-iter x AND W (round-1 dropped it; compiler rolled the
// loop at 44 VGPRs and stalled on L2 latency every iter).
// __launch_bounds__(256,4) caps VGPR at 128 -> 4 blocks/CU, 4 waves/SIMD.
// x read once from HBM (134 MB); W (512 KB) L2-resident, no LDS staging.
//
// Reduction tree RACE FIX (round-2 failure): within a barrier interval no
// wave may write a slot that another wave reads. Wave 1 now rewrites its
// OWN slot (1), and wave 0 consumes it after the barrier:
//   phase1: w2->slot0, w3->slot1            | barrier
//   phase2: w0 += slot0; w1 += slot1, WR(1) | barrier   (w1 rewrites own slot)
//   phase3: w0 += slot1  -> w0+w1+w2+w3
// Wave 0 then routes its 16 tokens in-register (8-lane shfl_xor butterflies).
// ---------------------------------------------------------------------------
__global__ __launch_bounds__(256, 4) void k_gemm_route(
    const float* __restrict__ x, const float* __restrict__ W,
    float* __restrict__ p1o, float* __restrict__ p2o,
    int* __restrict__ top1o, int* __restrict__ top2o)
{
    __shared__ float red[2 * 1024];   // 2 slots x (16 tok x 64 e) = 8 KB

    const int tid  = threadIdx.x;
    const int w    = tid >> 6;        // wave index 0..3 == k-chunk
    const int lane = tid & 63;
    const int tg   = lane >> 3;       // token group 0..7 (2 tokens each)
    const int eg   = lane & 7;        // expert group 0..7 (8 experts each)
    const int tok0 = blockIdx.x * 16;

    const float* xb = x + (size_t)(tok0 + tg * 2) * HID + w * 512;
    const float* wb = W + (size_t)(w * 512) * EXPERTS + eg * 8;

    float acc[2][8];
    #pragma unroll
    for (int i = 0; i < 2; ++i)
        #pragma unroll
        for (int j = 0; j < 8; ++j) acc[i][j] = 0.f;

    // prologue: load k4=0 operands
    float4 xv[2], w0c[4], w1c[4];
    #pragma unroll
    for (int i = 0; i < 2; ++i)
        xv[i] = *(const float4*)(xb + (size_t)i * HID);
    #pragma unroll
    for (int kk = 0; kk < 4; ++kk) {
        const float* wp = wb + (size_t)kk * EXPERTS;
        w0c[kk] = *(const float4*)wp;
        w1c[kk] = *(const float4*)(wp + 4);
    }

    #pragma unroll 2
    for (int k4 = 0; k4 < 512; k4 += 4) {
        const bool more = (k4 + 4 < 512);
        float4 xn[2], wn0[4], wn1[4];
        if (more) {
            #pragma unroll
            for (int i = 0; i < 2; ++i)
                xn[i] = *(const float4*)(xb + (size_t)i * HID + k4 + 4);
            #pragma unroll
            for (int kk = 0; kk < 4; ++kk) {
                const float* wp = wb + (size_t)(k4 + 4 + kk) * EXPERTS;
                wn0[kk] = *(const float4*)wp;
                wn1[kk] = *(const float4*)(wp + 4);
            }
        }

        #pragma unroll
        for (int i = 0; i < 2; ++i) {
            fma8(acc[i], xv[i].x, w0c[0], w1c[0]);
            fma8(acc[i], xv[i].y, w0c[1], w1c[1]);
            fma8(acc[i], xv[i].z, w0c[2], w1c[2]);
            fma8(acc[i], xv[i].w, w0c[3], w1c[3]);
        }

        if (more) {
            #pragma unroll
            for (int i = 0; i < 2; ++i) xv[i] = xn[i];
            #pragma unroll
            for (int kk = 0; kk < 4; ++kk) { w0c[kk] = wn0[kk]; w1c[kk] = wn1[kk]; }
        }
    }

    // ---- deterministic tree reduction over the 4 chunk-waves ----
    // Per slot: 1024 floats; lane writes 4 float4s at [q*256 + lane*4]
    // (16 B/lane consecutive -> conflict-free b128 pattern).
    auto WR = [&](int slot) {
        float* b = red + slot * 1024 + lane * 4;
        #pragma unroll
        for (int q = 0; q < 4; ++q) {
            const int i = q >> 1, j0 = (q & 1) * 4;
            *(float4*)(b + q * 256) = make_float4(
                acc[i][j0 + 0], acc[i][j0 + 1], acc[i][j0 + 2], acc[i][j0 + 3]);
        }
    };
    auto AD = [&](int slot) {
        const float* b = red + slot * 1024 + lane * 4;
        #pragma unroll
        for (int q = 0; q < 4; ++q) {
            const int i = q >> 1, j0 = (q & 1) * 4;
            float4 r = *(const float4*)(b + q * 256);
            acc[i][j0 + 0] += r.x; acc[i][j0 + 1] += r.y;
            acc[i][j0 + 2] += r.z; acc[i][j0 + 3] += r.w;
        }
    };

    if (w >= 2) WR(w - 2);                       // w2 -> slot0, w3 -> slot1
    __syncthreads();
    if (w < 2) { AD(w); if (w == 1) WR(1); }     // w0+=s0; w1+=s1, rewrites OWN slot
    __syncthreads();

    if (w == 0) {
        AD(1);  // wave 0 now holds final logits for its 16 tokens

        // ---- fused route: per token, 8 in-lane values x 8 eg-lanes ----
        #pragma unroll
        for (int i = 0; i < 2; ++i) {
            // top-1 argmax, first-index tie-break
            float bv = acc[i][0]; int be = eg * 8;
            #pragma unroll
            for (int j = 1; j < 8; ++j)
                if (acc[i][j] > bv) { bv = acc[i][j]; be = eg * 8 + j; }
            #pragma unroll
            for (int m = 1; m <= 4; m <<= 1) {
                float ov = __shfl_xor(bv, m);
                int   oe = __shfl_xor(be, m);
                if (ov > bv || (ov == bv && oe < be)) { bv = ov; be = oe; }
            }
            const float m1 = bv;
            const int   e1 = be;

            // top-2: argmax excluding e1
            float bv2 = -INFINITY; int be2 = 1 << 30;
            #pragma unroll
            for (int j = 0; j < 8; ++j) {
                const int e = eg * 8 + j;
                if (e != e1 && acc[i][j] > bv2) { bv2 = acc[i][j]; be2 = e; }
            }
            #pragma unroll
            for (int m = 1; m <= 4; m <<= 1) {
                float ov = __shfl_xor(bv2, m);
                int   oe = __shfl_xor(be2, m);
                if (ov > bv2 || (ov == bv2 && oe < be2)) { bv2 = ov; be2 = oe; }
            }

            // softmax denominator (max-subtracted)
            float s = 0.f;
            #pragma unroll
            for (int j = 0; j < 8; ++j) s += expf(acc[i][j] - m1);
            #pragma unroll
            for (int m = 1; m <= 4; m <<= 1) s += __shfl_xor(s, m);

            if (eg == 0) {
                const int t = tok0 + tg * 2 + i;
                p1o[t]   = 1.0f / s;
                p2o[t]   = expf(bv2 - m1) / s;
                top1o[t] = e1;
                top2o[t] = be2;
            }
        }
    }
}

// ---------------------------------------------------------------------------
// K2: per-expert batch-prioritized ranking -> keep flags. 128 blocks:
// block e<64 ranks expert e's top-1 list; block 64+e ranks expert e's
// top-2 list (counting raw top-1 matches in the SAME vectorized scan).
// Single int4-vectorized pass over all tokens (16 loop iters vs 64 scalar),
// list built in LDS with block-local atomics, then O(n^2) rank
// (n ~ 256, LDS-broadcast inner loop).
// rank(t) = #{t' in same list : p1[t'] > p1[t] or (== and t' < t)}
// keep1: rank1 < CAP.  keep2: rank2 + n1_raw (pre-drop top1 count) < CAP.
// ---------------------------------------------------------------------------
__global__ __launch_bounds__(256) void k_rank(
    const float* __restrict__ p1,
    const int* __restrict__ top1, const int* __restrict__ top2,
    int* __restrict__ keep1, int* __restrict__ keep2)
{
    __shared__ float skey[CAPSLOT];
    __shared__ int   stok[CAPSLOT];
    __shared__ int   cnt;
    __shared__ int   cnt1;

    const int e    = blockIdx.x & 63;
    const int mode = blockIdx.x >> 6;   // 0: top-1 ranking, 1: top-2 ranking
    const int tid  = threadIdx.x;

    if (tid == 0) { cnt = 0; cnt1 = 0; }
    __syncthreads();

    const int* __restrict__ sel = mode ? top2 : top1;
    int c1local = 0;
    for (int t0 = tid * 4; t0 < TOKENS; t0 += 1024) {
        const int4 sv = *(const int4*)(sel + t0);
        if (mode) {
            const int4 t1v = *(const int4*)(top1 + t0);
            c1local += (t1v.x == e) + (t1v.y == e) + (t1v.z == e) + (t1v.w == e);
        }
        const int s[4] = { sv.x, sv.y, sv.z, sv.w };
        #pragma unroll
        for (int j = 0; j < 4; ++j) {
            if (s[j] == e) {
                int i = atomicAdd(&cnt, 1);
                if (i < CAPSLOT) { stok[i] = t0 + j; skey[i] = p1[t0 + j]; }
            }
        }
    }
    if (mode && c1local) atomicAdd(&cnt1, c1local);
    __syncthreads();

    const int n_raw = cnt;
    const int n     = min(n_raw, CAPSLOT);
    const int base  = mode ? cnt1 : 0;   // top-2 ranks offset by raw top-1 count
    int* __restrict__ keep = mode ? keep2 : keep1;

    for (int i = tid; i < n; i += 256) {
        const float ki = skey[i];
        const int   ti = stok[i];
        int r = base;
        for (int j = 0; j < n; ++j)
            r += (skey[j] > ki || (skey[j] == ki && stok[j] < ti)) ? 1 : 0;
        keep[ti] = (r < CAP) ? 1 : 0;
    }
}

// ---------------------------------------------------------------------------
// K3: materialize [top_1_mask | gates], coalesced (16 threads per token row).
// ---------------------------------------------------------------------------
__global__ __launch_bounds__(256) void k_out(
    const float* __restrict__ p1, const float* __restrict__ p2,
    const int* __restrict__ top1, const int* __restrict__ top2,
    const int* __restrict__ keep1, const int* __restrict__ keep2,
    float* __restrict__ out)
{
    const int tid   = threadIdx.x;
    const int token = blockIdx.x * 16 + (tid >> 4);
    const int eb    = (tid & 15) * 4;

    const int  k1 = keep1[token];
    const int  k2 = keep2[token];
    const float P1 = k1 ? p1[token] : 0.0f;
    const float P2 = k2 ? p2[token] : 0.0f;
    const float denom = fmaxf(P1 + P2, 1.1920929e-07f);   // fp32 eps clip
    const float g1 = P1 / denom;
    const float g2 = P2 / denom;
    const int e1 = top1[token];
    const int e2 = top2[token];

    float4 mv, pv;
    mv.x = (k1 && e1 == eb + 0) ? 1.0f : 0.0f;
    mv.y = (k1 && e1 == eb + 1) ? 1.0f : 0.0f;
    mv.z = (k1 && e1 == eb + 2) ? 1.0f : 0.0f;
    mv.w = (k1 && e1 == eb + 3) ? 1.0f : 0.0f;
    pv.x = (k1 && e1 == eb + 0) ? g1 : ((k2 && e2 == eb + 0) ? g2 : 0.0f);
    pv.y = (k1 && e1 == eb + 1) ? g1 : ((k2 && e2 == eb + 1) ? g2 : 0.0f);
    pv.z = (k1 && e1 == eb + 2) ? g1 : ((k2 && e2 == eb + 2) ? g2 : 0.0f);
    pv.w = (k1 && e1 == eb + 3) ? g1 : ((k2 && e2 == eb + 3) ? g2 : 0.0f);

    *(float4*)(out + (size_t)token * EXPERTS + eb) = mv;
    *(float4*)(out + (size_t)TOKENS * EXPERTS + (size_t)token * EXPERTS + eb) = pv;
}

// ---------------------------------------------------------------------------
extern "C" void kernel_launch(void* const* d_in, const int* in_sizes, int n_in,
                              void* d_out, int out_size, void* d_ws, size_t ws_size,
                              hipStream_t stream)
{
    const float* x = (const float*)d_in[0];   // (8,2048,2048) fp32
    const float* W = (const float*)d_in[1];   // (2048,64) fp32
    float* out = (float*)d_out;               // 2 * 16384 * 64 fp32

    // workspace layout (~0.4 MB)
    float* p1    = (float*)d_ws;
    float* p2    = p1 + TOKENS;
    int*   top1  = (int*)(p2 + TOKENS);
    int*   top2  = top1 + TOKENS;
    int*   keep1 = top2 + TOKENS;
    int*   keep2 = keep1 + TOKENS;

    k_gemm_route<<<TOKENS / 16, 256, 0, stream>>>(x, W, p1, p2, top1, top2);
    k_rank<<<2 * EXPERTS, 256, 0, stream>>>(p1, top1, top2, keep1, keep2);
    k_out<<<TOKENS / 16, 256, 0, stream>>>(
        p1, p2, top1, top2, keep1, keep2, out);
}

// Round 4
// 352.014 us; speedup vs baseline: 1.9729x; 1.9729x over previous
//
#include <hip/hip_runtime.h>
#include <math.h>

// Problem constants (fixed by reference).
#define TOKENS      16384     // 8 * 2048
#define HID         2048
#define EXPERTS     64
#define CAPSLOT     1024      // per-expert list cap; counts ~Binom(16384,1/64)=256±16
#define CAP         512       // expert_capacity = 2*ceil(16384/64)

__device__ __forceinline__ void fma8(float* a, float s, float4 w0, float4 w1) {
    a[0] = fmaf(s, w0.x, a[0]); a[1] = fmaf(s, w0.y, a[1]);
    a[2] = fmaf(s, w0.z, a[2]); a[3] = fmaf(s, w0.w, a[3]);
    a[4] = fmaf(s, w1.x, a[4]); a[5] = fmaf(s, w1.y, a[5]);
    a[6] = fmaf(s, w1.z, a[6]); a[7] = fmaf(s, w1.w, a[7]);
}

// ---------------------------------------------------------------------------
// K1: fused logits GEMM + softmax + top1/top2 routing + bucket append.
// Grid = 1024 blocks x 256 threads (4 waves). Block owns 16 tokens, full K.
// Wave w computes k-chunk [w*512, w*512+512): thread tile 2 tok x 8 exp.
//
// ROUND-3 POST-MORTEM: #pragma unroll 2 + prefetch arrays duplicated live
// ranges past the 128-VGPR cap of __launch_bounds__(256,4) -> RA spilled to
// scratch (WRITE_SIZE 748 MB, VGPR 64, VALUBusy 7%). Fix: true A/B
// ping-pong (no copy movs, no unroll pragma; live ~125 regs) and
// __launch_bounds__(256,3) -> cap ~170, no spill, 3-4 waves/SIMD.
//
// Reduction tree (race-fixed in round 3, PASSED): within a barrier interval
// no wave writes a slot another wave reads:
//   phase1: w2->slot0, w3->slot1            | barrier
//   phase2: w0 += slot0; w1 += slot1, WR(1) | barrier
//   phase3: w0 += slot1
// Wave 0 routes its 16 tokens in-register, writes p1/p2/top1/top2, and
// APPENDS (p1, token) to per-expert bucket lists via global atomics
// (line-padded counters; ~32K atomics total) so k_rank needs no token scan.
// ---------------------------------------------------------------------------
__global__ __launch_bounds__(256, 3) void k_gemm_route(
    const float* __restrict__ x, const float* __restrict__ W,
    float* __restrict__ p1o, float* __restrict__ p2o,
    int* __restrict__ top1o, int* __restrict__ top2o,
    int* __restrict__ cnts,            // [128 * 16] line-padded counters
    float* __restrict__ bkey,          // [128 * CAPSLOT] sort keys (p1)
    int* __restrict__ btok)            // [128 * CAPSLOT] token ids
{
    __shared__ float red[2 * 1024];   // 2 slots x (16 tok x 64 e) = 8 KB

    const int tid  = threadIdx.x;
    const int w    = tid >> 6;        // wave index 0..3 == k-chunk
    const int lane = tid & 63;
    const int tg   = lane >> 3;       // token group 0..7 (2 tokens each)
    const int eg   = lane & 7;        // expert group 0..7 (8 experts each)
    const int tok0 = blockIdx.x * 16;

    const float* xb = x + (size_t)(tok0 + tg * 2) * HID + w * 512;
    const float* wb = W + (size_t)(w * 512) * EXPERTS + eg * 8;

    float acc[2][8];
    #pragma unroll
    for (int i = 0; i < 2; ++i)
        #pragma unroll
        for (int j = 0; j < 8; ++j) acc[i][j] = 0.f;

    // ping-pong buffers
    float4 xA[2], wA0[4], wA1[4];
    float4 xB[2], wB0[4], wB1[4];

    auto LDX = [&](float4* d, int k) {
        d[0] = *(const float4*)(xb + k);
        d[1] = *(const float4*)(xb + HID + k);
    };
    auto LDW = [&](float4* d0, float4* d1, int k) {
        #pragma unroll
        for (int kk = 0; kk < 4; ++kk) {
            const float* wp = wb + (size_t)(k + kk) * EXPERTS;
            d0[kk] = *(const float4*)wp;
            d1[kk] = *(const float4*)(wp + 4);
        }
    };
    auto FMA = [&](const float4* xv, const float4* w0, const float4* w1) {
        #pragma unroll
        for (int i = 0; i < 2; ++i) {
            fma8(acc[i], xv[i].x, w0[0], w1[0]);
            fma8(acc[i], xv[i].y, w0[1], w1[1]);
            fma8(acc[i], xv[i].z, w0[2], w1[2]);
            fma8(acc[i], xv[i].w, w0[3], w1[3]);
        }
    };

    LDX(xA, 0); LDW(wA0, wA1, 0);
    for (int k4 = 0; k4 < 512; k4 += 8) {
        LDX(xB, k4 + 4); LDW(wB0, wB1, k4 + 4);     // prefetch B
        FMA(xA, wA0, wA1);                           // compute A
        if (k4 < 504) { LDX(xA, k4 + 8); LDW(wA0, wA1, k4 + 8); } // prefetch A'
        FMA(xB, wB0, wB1);                           // compute B
    }

    // ---- deterministic tree reduction over the 4 chunk-waves ----
    auto WR = [&](int slot) {
        float* b = red + slot * 1024 + lane * 4;
        #pragma unroll
        for (int q = 0; q < 4; ++q) {
            const int i = q >> 1, j0 = (q & 1) * 4;
            *(float4*)(b + q * 256) = make_float4(
                acc[i][j0 + 0], acc[i][j0 + 1], acc[i][j0 + 2], acc[i][j0 + 3]);
        }
    };
    auto AD = [&](int slot) {
        const float* b = red + slot * 1024 + lane * 4;
        #pragma unroll
        for (int q = 0; q < 4; ++q) {
            const int i = q >> 1, j0 = (q & 1) * 4;
            float4 r = *(const float4*)(b + q * 256);
            acc[i][j0 + 0] += r.x; acc[i][j0 + 1] += r.y;
            acc[i][j0 + 2] += r.z; acc[i][j0 + 3] += r.w;
        }
    };

    if (w >= 2) WR(w - 2);                       // w2 -> slot0, w3 -> slot1
    __syncthreads();
    if (w < 2) { AD(w); if (w == 1) WR(1); }     // w0+=s0; w1+=s1, rewrites OWN slot
    __syncthreads();

    if (w == 0) {
        AD(1);  // wave 0 now holds final logits for its 16 tokens

        #pragma unroll
        for (int i = 0; i < 2; ++i) {
            // top-1 argmax, first-index tie-break
            float bv = acc[i][0]; int be = eg * 8;
            #pragma unroll
            for (int j = 1; j < 8; ++j)
                if (acc[i][j] > bv) { bv = acc[i][j]; be = eg * 8 + j; }
            #pragma unroll
            for (int m = 1; m <= 4; m <<= 1) {
                float ov = __shfl_xor(bv, m);
                int   oe = __shfl_xor(be, m);
                if (ov > bv || (ov == bv && oe < be)) { bv = ov; be = oe; }
            }
            const float m1 = bv;
            const int   e1 = be;

            // top-2: argmax excluding e1
            float bv2 = -INFINITY; int be2 = 1 << 30;
            #pragma unroll
            for (int j = 0; j < 8; ++j) {
                const int e = eg * 8 + j;
                if (e != e1 && acc[i][j] > bv2) { bv2 = acc[i][j]; be2 = e; }
            }
            #pragma unroll
            for (int m = 1; m <= 4; m <<= 1) {
                float ov = __shfl_xor(bv2, m);
                int   oe = __shfl_xor(be2, m);
                if (ov > bv2 || (ov == bv2 && oe < be2)) { bv2 = ov; be2 = oe; }
            }

            // softmax denominator (max-subtracted)
            float s = 0.f;
            #pragma unroll
            for (int j = 0; j < 8; ++j) s += expf(acc[i][j] - m1);
            #pragma unroll
            for (int m = 1; m <= 4; m <<= 1) s += __shfl_xor(s, m);

            if (eg == 0) {
                const int t  = tok0 + tg * 2 + i;
                const float P1 = 1.0f / s;       // max softmax prob (sort key)
                p1o[t]   = P1;
                p2o[t]   = expf(bv2 - m1) / s;
                top1o[t] = e1;
                top2o[t] = be2;

                // bucket appends (order-independent rank later)
                int s1 = atomicAdd(&cnts[e1 * 16], 1);
                if (s1 < CAPSLOT) {
                    bkey[(size_t)e1 * CAPSLOT + s1] = P1;
                    btok[(size_t)e1 * CAPSLOT + s1] = t;
                }
                int s2 = atomicAdd(&cnts[(64 + be2) * 16], 1);
                if (s2 < CAPSLOT) {
                    bkey[(size_t)(64 + be2) * CAPSLOT + s2] = P1;
                    btok[(size_t)(64 + be2) * CAPSLOT + s2] = t;
                }
            }
        }
    }
}

// ---------------------------------------------------------------------------
// K2: per-expert batch-prioritized ranking -> keep flags. 128 blocks
// (b<64: expert b's top-1 list; b>=64: expert (b-64)'s top-2 list).
// NO token scan: reads its pre-built bucket (~256 entries), O(n^2) rank.
// rank(t) = #{t' in same list : p1[t'] > p1[t] or (== and t' < t)}
// keep1: rank1 < CAP.  keep2: rank2 + n1_raw (pre-drop top1 count) < CAP.
// Bucket fill order is nondeterministic but the rank comparator
// (key desc, token asc) is a strict total order -> result deterministic.
// ---------------------------------------------------------------------------
__global__ __launch_bounds__(256) void k_rank(
    const int* __restrict__ cnts,
    const float* __restrict__ bkey, const int* __restrict__ btok,
    int* __restrict__ keep1, int* __restrict__ keep2)
{
    __shared__ float skey[CAPSLOT];
    __shared__ int   stok[CAPSLOT];

    const int b    = blockIdx.x;
    const int mode = b >> 6;
    const int e    = b & 63;
    const int tid  = threadIdx.x;

    const int n_raw = cnts[b * 16];
    const int n     = min(n_raw, CAPSLOT);
    const int base  = mode ? cnts[e * 16] : 0;   // raw top-1 count offset

    for (int i = tid; i < n; i += 256) {
        skey[i] = bkey[(size_t)b * CAPSLOT + i];
        stok[i] = btok[(size_t)b * CAPSLOT + i];
    }
    __syncthreads();

    int* __restrict__ keep = mode ? keep2 : keep1;
    for (int i = tid; i < n; i += 256) {
        const float ki = skey[i];
        const int   ti = stok[i];
        int r = base;
        for (int j = 0; j < n; ++j)
            r += (skey[j] > ki || (skey[j] == ki && stok[j] < ti)) ? 1 : 0;
        keep[ti] = (r < CAP) ? 1 : 0;
    }
}

// ---------------------------------------------------------------------------
// K3: materialize [top_1_mask | gates], coalesced (16 threads per token row).
// ---------------------------------------------------------------------------
__global__ __launch_bounds__(256) void k_out(
    const float* __restrict__ p1, const float* __restrict__ p2,
    const int* __restrict__ top1, const int* __restrict__ top2,
    const int* __restrict__ keep1, const int* __restrict__ keep2,
    float* __restrict__ out)
{
    const int tid   = threadIdx.x;
    const int token = blockIdx.x * 16 + (tid >> 4);
    const int eb    = (tid & 15) * 4;

    const int  k1 = keep1[token];
    const int  k2 = keep2[token];
    const float P1 = k1 ? p1[token] : 0.0f;
    const float P2 = k2 ? p2[token] : 0.0f;
    const float denom = fmaxf(P1 + P2, 1.1920929e-07f);   // fp32 eps clip
    const float g1 = P1 / denom;
    const float g2 = P2 / denom;
    const int e1 = top1[token];
    const int e2 = top2[token];

    float4 mv, pv;
    mv.x = (k1 && e1 == eb + 0) ? 1.0f : 0.0f;
    mv.y = (k1 && e1 == eb + 1) ? 1.0f : 0.0f;
    mv.z = (k1 && e1 == eb + 2) ? 1.0f : 0.0f;
    mv.w = (k1 && e1 == eb + 3) ? 1.0f : 0.0f;
    pv.x = (k1 && e1 == eb + 0) ? g1 : ((k2 && e2 == eb + 0) ? g2 : 0.0f);
    pv.y = (k1 && e1 == eb + 1) ? g1 : ((k2 && e2 == eb + 1) ? g2 : 0.0f);
    pv.z = (k1 && e1 == eb + 2) ? g1 : ((k2 && e2 == eb + 2) ? g2 : 0.0f);
    pv.w = (k1 && e1 == eb + 3) ? g1 : ((k2 && e2 == eb + 3) ? g2 : 0.0f);

    *(float4*)(out + (size_t)token * EXPERTS + eb) = mv;
    *(float4*)(out + (size_t)TOKENS * EXPERTS + (size_t)token * EXPERTS + eb) = pv;
}

// ---------------------------------------------------------------------------
extern "C" void kernel_launch(void* const* d_in, const int* in_sizes, int n_in,
                              void* d_out, int out_size, void* d_ws, size_t ws_size,
                              hipStream_t stream)
{
    const float* x = (const float*)d_in[0];   // (8,2048,2048) fp32
    const float* W = (const float*)d_in[1];   // (2048,64) fp32
    float* out = (float*)d_out;               // 2 * 16384 * 64 fp32

    // workspace layout (~1.4 MB)
    float* p1    = (float*)d_ws;
    float* p2    = p1 + TOKENS;
    int*   top1  = (int*)(p2 + TOKENS);
    int*   top2  = top1 + TOKENS;
    int*   keep1 = top2 + TOKENS;
    int*   keep2 = keep1 + TOKENS;
    int*   cnts  = keep2 + TOKENS;            // 128 * 16 ints (line-padded)
    float* bkey  = (float*)(cnts + 128 * 16); // 128 * CAPSLOT floats
    int*   btok  = (int*)(bkey + 128 * CAPSLOT);

    hipMemsetAsync(cnts, 0, 128 * 16 * sizeof(int), stream);
    k_gemm_route<<<TOKENS / 16, 256, 0, stream>>>(
        x, W, p1, p2, top1, top2, cnts, bkey, btok);
    k_rank<<<2 * EXPERTS, 256, 0, stream>>>(cnts, bkey, btok, keep1, keep2);
    k_out<<<TOKENS / 16, 256, 0, stream>>>(
        p1, p2, top1, top2, keep1, keep2, out);
}

// Round 5
// 258.388 us; speedup vs baseline: 2.6877x; 1.3623x over previous
//
#include <hip/hip_runtime.h>
#include <math.h>

// Problem constants (fixed by reference).
#define TOKENS      16384     // 8 * 2048
#define HID         2048
#define EXPERTS     64
#define CAPSLOT     1024      // per-expert list cap; counts ~Binom(16384,1/64)=256±16
#define CAP         512       // expert_capacity = 2*ceil(16384/64)

__device__ __forceinline__ void fma8(float* a, float s, float4 w0, float4 w1) {
    a[0] = fmaf(s, w0.x, a[0]); a[1] = fmaf(s, w0.y, a[1]);
    a[2] = fmaf(s, w0.z, a[2]); a[3] = fmaf(s, w0.w, a[3]);
    a[4] = fmaf(s, w1.x, a[4]); a[5] = fmaf(s, w1.y, a[5]);
    a[6] = fmaf(s, w1.z, a[6]); a[7] = fmaf(s, w1.w, a[7]);
}

// ---------------------------------------------------------------------------
// K1: partial logits GEMM (round-0 proven structure, occupancy-doubled).
// Template KCH = k per chunk; KSPLIT = HID/KCH blocks per 256-token group.
// Grid = 64 token-groups x KSPLIT. W chunk (KCH x 64 = KCH*256 B) staged to
// LDS once (single barrier), then a BARRIER-FREE k-loop: x per-lane float4
// from global (prefetch-1), W via ds_read_b128 broadcast from LDS.
// Thread tile: 8 tokens x 8 experts = 64 fp32 acc (this tile keeps the LDS
// pipe under the VALU pipe: per k4-step 8 ds_read_b128 (~96 CU-cyc) vs 256
// FMA instr (512 SIMD-cyc); smaller token tiles go LDS-bound).
//
// SESSION EVIDENCE: W-from-L2 designs (r1-r4) = 140-197us, VALUBusy <=25%;
// this W-in-LDS design = 95us at KCH=512 / 1 block/CU / VALUBusy 35% (r0).
// KCH=256 halves LDS to 64KB -> 2 blocks/CU -> 2 waves/SIMD, which is the
// only thing round-0 was missing. Block 0 also zeroes the bucket counters
// (saves the memset dispatch; k_route runs strictly after in-stream order).
// ---------------------------------------------------------------------------
template<int KCH>
__global__ __launch_bounds__(256) void k_partial(
    const float* __restrict__ x, const float* __restrict__ W,
    float* __restrict__ partial, int* __restrict__ cnts)
{
    __shared__ float wl[KCH * EXPERTS];   // 64 KB (KCH=256) / 128 KB (512)

    const int tid = threadIdx.x;
    const int tb = blockIdx.x & 63;       // token block (256 tokens)
    const int kc = blockIdx.x >> 6;       // k chunk
    const int k0 = kc * KCH;

    if (blockIdx.x == 0) {                // zero bucket counters for k_route
        for (int i = tid; i < 128 * 16; i += 256) cnts[i] = 0;
    }

    // stage W chunk, coalesced float4
    {
        const float4* src = (const float4*)(W + (size_t)k0 * EXPERTS);
        float4* dst = (float4*)wl;
        #pragma unroll
        for (int i = 0; i < (KCH * EXPERTS / 4) / 256; ++i)
            dst[i * 256 + tid] = src[i * 256 + tid];
    }
    __syncthreads();

    const int lane = tid & 63;
    const int wv   = tid >> 6;            // wave 0..3
    const int tg   = lane >> 3;           // token group 0..7
    const int eg   = lane & 7;            // expert group 0..7 (experts 8eg..)
    const int tok0 = tb * 256 + wv * 64 + tg * 8;
    const float* xb = x + (size_t)tok0 * HID + k0;

    float acc[8][8];
    #pragma unroll
    for (int i = 0; i < 8; ++i)
        #pragma unroll
        for (int e = 0; e < 8; ++e) acc[i][e] = 0.f;

    float4 xv[8];
    #pragma unroll
    for (int i = 0; i < 8; ++i)
        xv[i] = *(const float4*)(xb + (size_t)i * HID);

    #pragma unroll 2
    for (int k4 = 0; k4 < KCH; k4 += 4) {
        float4 xn[8];
        const bool more = (k4 + 4 < KCH);
        if (more) {
            #pragma unroll
            for (int i = 0; i < 8; ++i)
                xn[i] = *(const float4*)(xb + (size_t)i * HID + k4 + 4);
        }

        float4 w0[4], w1[4];
        #pragma unroll
        for (int kk = 0; kk < 4; ++kk) {
            const float* wp = &wl[(k4 + kk) * EXPERTS + eg * 8];
            w0[kk] = *(const float4*)wp;
            w1[kk] = *(const float4*)(wp + 4);
        }

        #pragma unroll
        for (int i = 0; i < 8; ++i) {
            fma8(acc[i], xv[i].x, w0[0], w1[0]);
            fma8(acc[i], xv[i].y, w0[1], w1[1]);
            fma8(acc[i], xv[i].z, w0[2], w1[2]);
            fma8(acc[i], xv[i].w, w0[3], w1[3]);
        }

        if (more) {
            #pragma unroll
            for (int i = 0; i < 8; ++i) xv[i] = xn[i];
        }
    }

    float* pb = partial + ((size_t)kc * TOKENS + tok0) * EXPERTS + eg * 8;
    #pragma unroll
    for (int i = 0; i < 8; ++i) {
        *(float4*)(pb + (size_t)i * EXPERTS) =
            make_float4(acc[i][0], acc[i][1], acc[i][2], acc[i][3]);
        *(float4*)(pb + (size_t)i * EXPERTS + 4) =
            make_float4(acc[i][4], acc[i][5], acc[i][6], acc[i][7]);
    }
}

// ---------------------------------------------------------------------------
// K2: reduce k-chunks + softmax + top1/top2 + bucket append.
// Wave = 1 token x 64 expert lanes (round-1 proven butterflies); lane 0
// appends (p1, token) to the per-expert bucket lists via global atomics
// (line-padded counters) so k_rank needs no token scan (round-4 proven).
// ---------------------------------------------------------------------------
template<int KSPLIT>
__global__ __launch_bounds__(256) void k_route(
    const float* __restrict__ partial,
    float* __restrict__ p1o, float* __restrict__ p2o,
    int* __restrict__ top1o, int* __restrict__ top2o,
    int* __restrict__ cnts, float* __restrict__ bkey, int* __restrict__ btok)
{
    const int tid   = threadIdx.x;
    const int e     = tid & 63;
    const int token = blockIdx.x * 4 + (tid >> 6);

    float logit = 0.f;
    #pragma unroll
    for (int c = 0; c < KSPLIT; ++c)
        logit += partial[((size_t)c * TOKENS + token) * EXPERTS + e];

    // top-1 argmax, first-index tie-break
    float bv = logit; int be = e;
    #pragma unroll
    for (int m = 32; m >= 1; m >>= 1) {
        float ov = __shfl_xor(bv, m);
        int   oe = __shfl_xor(be, m);
        if (ov > bv || (ov == bv && oe < be)) { bv = ov; be = oe; }
    }
    const float m1 = bv;
    const int   e1 = be;

    // top-2: argmax excluding e1
    float bv2 = (e == e1) ? -INFINITY : logit;
    int   be2 = (e == e1) ? (1 << 30) : e;
    #pragma unroll
    for (int m = 32; m >= 1; m >>= 1) {
        float ov = __shfl_xor(bv2, m);
        int   oe = __shfl_xor(be2, m);
        if (ov > bv2 || (ov == bv2 && oe < be2)) { bv2 = ov; be2 = oe; }
    }
    const int e2 = be2;

    // softmax denominator (max-subtracted)
    float s = expf(logit - m1);
    #pragma unroll
    for (int m = 32; m >= 1; m >>= 1) s += __shfl_xor(s, m);

    if (e == 0) {
        const float P1 = 1.0f / s;          // max softmax prob (sort key)
        p1o[token]   = P1;
        p2o[token]   = expf(bv2 - m1) / s;
        top1o[token] = e1;
        top2o[token] = e2;

        // bucket appends (fill order nondeterministic; rank comparator
        // (key desc, token asc) is a strict total order -> deterministic)
        int s1 = atomicAdd(&cnts[e1 * 16], 1);
        if (s1 < CAPSLOT) {
            bkey[(size_t)e1 * CAPSLOT + s1] = P1;
            btok[(size_t)e1 * CAPSLOT + s1] = token;
        }
        int s2 = atomicAdd(&cnts[(64 + e2) * 16], 1);
        if (s2 < CAPSLOT) {
            bkey[(size_t)(64 + e2) * CAPSLOT + s2] = P1;
            btok[(size_t)(64 + e2) * CAPSLOT + s2] = token;
        }
    }
}

// ---------------------------------------------------------------------------
// K3: per-expert batch-prioritized ranking -> keep flags. 128 blocks
// (b<64: expert b's top-1 list; b>=64: expert (b-64)'s top-2 list).
// NO token scan: reads its pre-built bucket (~256 entries), O(n^2) rank.
// rank(t) = #{t' in same list : p1[t'] > p1[t] or (== and t' < t)}
// keep1: rank1 < CAP.  keep2: rank2 + n1_raw (pre-drop top1 count) < CAP.
// ---------------------------------------------------------------------------
__global__ __launch_bounds__(256) void k_rank(
    const int* __restrict__ cnts,
    const float* __restrict__ bkey, const int* __restrict__ btok,
    int* __restrict__ keep1, int* __restrict__ keep2)
{
    __shared__ float skey[CAPSLOT];
    __shared__ int   stok[CAPSLOT];

    const int b    = blockIdx.x;
    const int mode = b >> 6;
    const int e    = b & 63;
    const int tid  = threadIdx.x;

    const int n_raw = cnts[b * 16];
    const int n     = min(n_raw, CAPSLOT);
    const int base  = mode ? cnts[e * 16] : 0;   // raw top-1 count offset

    for (int i = tid; i < n; i += 256) {
        skey[i] = bkey[(size_t)b * CAPSLOT + i];
        stok[i] = btok[(size_t)b * CAPSLOT + i];
    }
    __syncthreads();

    int* __restrict__ keep = mode ? keep2 : keep1;
    for (int i = tid; i < n; i += 256) {
        const float ki = skey[i];
        const int   ti = stok[i];
        int r = base;
        for (int j = 0; j < n; ++j)
            r += (skey[j] > ki || (skey[j] == ki && stok[j] < ti)) ? 1 : 0;
        keep[ti] = (r < CAP) ? 1 : 0;
    }
}

// ---------------------------------------------------------------------------
// K4: materialize [top_1_mask | gates], coalesced (16 threads per token row).
// ---------------------------------------------------------------------------
__global__ __launch_bounds__(256) void k_out(
    const float* __restrict__ p1, const float* __restrict__ p2,
    const int* __restrict__ top1, const int* __restrict__ top2,
    const int* __restrict__ keep1, const int* __restrict__ keep2,
    float* __restrict__ out)
{
    const int tid   = threadIdx.x;
    const int token = blockIdx.x * 16 + (tid >> 4);
    const int eb    = (tid & 15) * 4;

    const int  k1 = keep1[token];
    const int  k2 = keep2[token];
    const float P1 = k1 ? p1[token] : 0.0f;
    const float P2 = k2 ? p2[token] : 0.0f;
    const float denom = fmaxf(P1 + P2, 1.1920929e-07f);   // fp32 eps clip
    const float g1 = P1 / denom;
    const float g2 = P2 / denom;
    const int e1 = top1[token];
    const int e2 = top2[token];

    float4 mv, pv;
    mv.x = (k1 && e1 == eb + 0) ? 1.0f : 0.0f;
    mv.y = (k1 && e1 == eb + 1) ? 1.0f : 0.0f;
    mv.z = (k1 && e1 == eb + 2) ? 1.0f : 0.0f;
    mv.w = (k1 && e1 == eb + 3) ? 1.0f : 0.0f;
    pv.x = (k1 && e1 == eb + 0) ? g1 : ((k2 && e2 == eb + 0) ? g2 : 0.0f);
    pv.y = (k1 && e1 == eb + 1) ? g1 : ((k2 && e2 == eb + 1) ? g2 : 0.0f);
    pv.z = (k1 && e1 == eb + 2) ? g1 : ((k2 && e2 == eb + 2) ? g2 : 0.0f);
    pv.w = (k1 && e1 == eb + 3) ? g1 : ((k2 && e2 == eb + 3) ? g2 : 0.0f);

    *(float4*)(out + (size_t)token * EXPERTS + eb) = mv;
    *(float4*)(out + (size_t)TOKENS * EXPERTS + (size_t)token * EXPERTS + eb) = pv;
}

// ---------------------------------------------------------------------------
extern "C" void kernel_launch(void* const* d_in, const int* in_sizes, int n_in,
                              void* d_out, int out_size, void* d_ws, size_t ws_size,
                              hipStream_t stream)
{
    const float* x = (const float*)d_in[0];   // (8,2048,2048) fp32
    const float* W = (const float*)d_in[1];   // (2048,64) fp32
    float* out = (float*)d_out;               // 2 * 16384 * 64 fp32

    // extras: p1,p2 (fp32) + top1,top2,keep1,keep2 (int) + cnts + buckets
    const size_t extras_f = 6 * (size_t)TOKENS        // 393 KB
                          + 128 * 16                   // cnts
                          + 2 * 128 * (size_t)CAPSLOT; // bkey+btok, 1 MB
    const size_t need8 = ((size_t)8 * TOKENS * EXPERTS + extras_f) * 4;
    const bool big = (ws_size == 0) || (ws_size >= need8);
    const int  ks  = big ? 8 : 4;   // fallback = round-0 proven config

    float* partial = (float*)d_ws;  // ks * TOKENS * EXPERTS floats
    float* p1    = partial + (size_t)ks * TOKENS * EXPERTS;
    float* p2    = p1 + TOKENS;
    int*   top1  = (int*)(p2 + TOKENS);
    int*   top2  = top1 + TOKENS;
    int*   keep1 = top2 + TOKENS;
    int*   keep2 = keep1 + TOKENS;
    int*   cnts  = keep2 + TOKENS;            // 128 * 16 ints (line-padded)
    float* bkey  = (float*)(cnts + 128 * 16); // 128 * CAPSLOT floats
    int*   btok  = (int*)(bkey + 128 * CAPSLOT);

    if (big) {
        k_partial<256><<<64 * 8, 256, 0, stream>>>(x, W, partial, cnts);
        k_route<8><<<TOKENS / 4, 256, 0, stream>>>(
            partial, p1, p2, top1, top2, cnts, bkey, btok);
    } else {
        k_partial<512><<<64 * 4, 256, 0, stream>>>(x, W, partial, cnts);
        k_route<4><<<TOKENS / 4, 256, 0, stream>>>(
            partial, p1, p2, top1, top2, cnts, bkey, btok);
    }
    k_rank<<<2 * EXPERTS, 256, 0, stream>>>(cnts, bkey, btok, keep1, keep2);
    k_out<<<TOKENS / 16, 256, 0, stream>>>(
        p1, p2, top1, top2, keep1, keep2, out);
}